// Round 1
// 412.140 us; speedup vs baseline: 1.0387x; 1.0387x over previous
//
#include <hip/hip_runtime.h>

// 2D Haar DWT: x (16,64,256,256) f32 -> out (16,256,128,128) f32.
// Pure bandwidth kernel: 256 MiB in + 256 MiB out; roofline ~85 us @ 6.3 TB/s.
//
// v2: each thread consumes 8 floats x 2 input rows (4 complete 2x2 blocks,
// 64 B read) and emits one float4 per subband plane (64 B written) via
// non-temporal dwordx4 stores. All loads/stores fully coalesced:
//   - loads: lanes 0..31 cover one full input row (2x 512 B segments/instr)
//   - stores: 32 consecutive lanes write 512 B contiguous per subband plane.
// Non-temporal on both streams: zero reuse, keep the 512 MiB out of L2.

using f32x4 = __attribute__((ext_vector_type(4))) float;

__global__ __launch_bounds__(256) void dwt_haar_kernel(
    const float* __restrict__ x, float* __restrict__ out) {
    const int n = blockIdx.x * blockDim.x + threadIdx.x;
    // n in [0, 1024 * 128 * 32)
    const int j4  = n & 31;        // float4 chunk along output width (128 floats = 32 chunks)
    const int rst = n >> 5;
    const int i   = rst & 127;     // output row
    const int bc  = rst >> 7;      // b*C + c, 0..1023

    const float* plane = x + (size_t)bc * (256 * 256);
    const f32x4* r0 = (const f32x4*)(plane + (2 * i)     * 256) + 2 * j4;
    const f32x4* r1 = (const f32x4*)(plane + (2 * i + 1) * 256) + 2 * j4;

    const f32x4 v0a = __builtin_nontemporal_load(r0);      // a0 b0 a1 b1
    const f32x4 v0b = __builtin_nontemporal_load(r0 + 1);  // a2 b2 a3 b3
    const f32x4 v1a = __builtin_nontemporal_load(r1);      // c0 d0 c1 d1
    const f32x4 v1b = __builtin_nontemporal_load(r1 + 1);  // c2 d2 c3 d3

    const f32x4 a = __builtin_shufflevector(v0a, v0b, 0, 2, 4, 6);
    const f32x4 b = __builtin_shufflevector(v0a, v0b, 1, 3, 5, 7);
    const f32x4 c = __builtin_shufflevector(v1a, v1b, 0, 2, 4, 6);
    const f32x4 d = __builtin_shufflevector(v1a, v1b, 1, 3, 5, 7);

    const f32x4 cA = (a + b + c + d) * 0.5f;
    const f32x4 cH = (c + d - a - b) * 0.5f;
    const f32x4 cV = (b + d - a - c) * 0.5f;
    const f32x4 cD = (a - b - c + d) * 0.5f;

    // out flat (floats): ((bc*4 + k)*128 + i)*128 + 4*j4
    // in float4 units:   (bc*4 + k)*4096 + i*32 + j4 ; subband plane stride = 4096.
    f32x4* o = (f32x4*)out + (size_t)bc * 4 * 4096 + (size_t)i * 32 + j4;
    __builtin_nontemporal_store(cA, o);
    __builtin_nontemporal_store(cH, o + 4096);
    __builtin_nontemporal_store(cV, o + 2 * 4096);
    __builtin_nontemporal_store(cD, o + 3 * 4096);
}

extern "C" void kernel_launch(void* const* d_in, const int* in_sizes, int n_in,
                              void* d_out, int out_size, void* d_ws, size_t ws_size,
                              hipStream_t stream) {
    const float* x = (const float*)d_in[0];
    float* out = (float*)d_out;
    // total threads = 1024 planes * 128 rows * 32 chunks = 4194304
    const int total = 1024 * 128 * 32;
    dwt_haar_kernel<<<total / 256, 256, 0, stream>>>(x, out);
}